// Round 6
// baseline (211.428 us; speedup 1.0000x reference)
//
#include <hip/hip_runtime.h>

// KAN-PINN forward, MI355X — round 6.
// A/B at small code size: K1 = layer1 with int-magic+NR reciprocal, i-loop
// NOT unrolled (I-cache hypothesis: r5's unroll2 body ~37KB > 32KB I$).
// K2 = layer2+head, exact r3 inner loop (hw v_rcp) as control.
// Fixed ~65us dur_us overhead is graph/harness-constant -> ignore dispatch count.

#define C2L 2.88539008177792681472f  // 2*log2(e)

__device__ __forceinline__ float rcp_nr(float d) {
  // 1/d, d in [1, ~1e9): int-magic seed + 2 Newton -> ~1e-6 rel err
  float r = __int_as_float(0x7EF311C2 - __float_as_int(d));
  r = r * fmaf(-d, r, 2.0f);
  r = r * fmaf(-d, r, 2.0f);
  return r;
}

__device__ __forceinline__ float tanh_hw(float z) {
  float e = __builtin_amdgcn_exp2f(z * C2L);
  float r = __builtin_amdgcn_rcpf(1.0f + e);
  return fmaf(r, -2.0f, 1.0f);
}

// ---------------- K0: layer0 + prep side tasks ----------------
__global__ __launch_bounds__(256) void kan_layer0(
    const float* __restrict__ x, const float* __restrict__ t,
    const float* __restrict__ W1, const float* __restrict__ B1,   // (64,2,8)
    const float* __restrict__ W2, const float* __restrict__ B2,   // (64,2,8),(64,2)
    const float* __restrict__ B1_1, const float* __restrict__ B1_2,
    const float* __restrict__ bout,
    float* __restrict__ hA,      // [64][8192] = C2L * h0
    float* __restrict__ B1c1, float* __restrict__ B1c2,
    float* __restrict__ out)     // (8192,) <- b_out
{
  const int tid  = threadIdx.x;
  const int lane = tid & 63;
  const int wave = __builtin_amdgcn_readfirstlane(tid >> 6);
  const int bx = blockIdx.x, by = blockIdx.y;
  const int flat = by * 128 + bx;

  if (flat < 128) {
    B1c1[flat * 256 + tid] = B1_1[flat * 256 + tid] * C2L;
  } else if (flat < 256) {
    B1c2[(flat - 128) * 256 + tid] = B1_2[(flat - 128) * 256 + tid] * C2L;
  } else if (flat < 288) {
    out[(flat - 256) * 256 + tid] = bout[0];
  }

  const int n  = bx * 64 + lane;
  const int j0 = by * 16 + wave * 4;
  const float hx = x[n], ht = t[n];
#pragma unroll
  for (int jj = 0; jj < 4; ++jj) {
    const int j = j0 + jj;
    float a0 = B2[j * 2 + 0];
    float a1 = B2[j * 2 + 1];
#pragma unroll
    for (int k = 0; k < 8; ++k) {
      float z0 = fmaf(hx, W1[j * 16 + k], B1[j * 16 + k]);
      a0 = fmaf(W2[j * 16 + k], tanh_hw(z0), a0);
      float z1 = fmaf(ht, W1[j * 16 + 8 + k], B1[j * 16 + 8 + k]);
      a1 = fmaf(W2[j * 16 + 8 + k], tanh_hw(z1), a1);
    }
    float y = a0 + a1;
    float e = __builtin_amdgcn_exp2f(y * C2L);
    float r = __builtin_amdgcn_rcpf(1.0f + e);
    hA[j * 8192 + n] = fmaf(r, -2.f * C2L, C2L);   // C2L * tanh(y)
  }
}

// ---------------- K1: layer1 (rcp_nr, small-code arm) ----------------
__global__ __launch_bounds__(256, 8) void kan_layer1(
    const float* __restrict__ hin,   // [64][8192] = C2L * h0
    const float* __restrict__ W1,    // (64,64,8)
    const float* __restrict__ B1c,   // (64,64,8) = C2L * B1
    const float* __restrict__ W2,    // (64,64,8)
    const float* __restrict__ B2,    // (64,64)
    float* __restrict__ hout)        // [64][8192] = C2L * h1
{
  __shared__ float hs[64][64];
  const int tid  = threadIdx.x;
  const int lane = tid & 63;
  const int wave = __builtin_amdgcn_readfirstlane(tid >> 6);
  const int n    = blockIdx.x * 64 + lane;

#pragma unroll
  for (int r = 0; r < 16; ++r) {
    const int i = r * 4 + wave;
    hs[i][lane] = hin[i * 8192 + n];
  }
  __syncthreads();

  const int j = blockIdx.y * 4 + wave;
  const float* __restrict__ w1p = W1  + j * 512;
  const float* __restrict__ b1p = B1c + j * 512;
  const float* __restrict__ w2p = W2  + j * 512;

  float sp = B2[j * 64 + lane];
  {
    const float4* w2v = (const float4*)w2p;
    float4 va = w2v[lane * 2 + 0];
    float4 vb = w2v[lane * 2 + 1];
    sp += (va.x + va.y) + (va.z + va.w) + (vb.x + vb.y) + (vb.z + vb.w);
  }
#pragma unroll
  for (int off = 32; off; off >>= 1) sp += __shfl_xor(sp, off);
  const float S = sp;

  float a0 = 0.f, a1 = 0.f, a2 = 0.f, a3 = 0.f;
  float a4 = 0.f, a5 = 0.f, a6 = 0.f, a7 = 0.f;
#pragma unroll 1
  for (int i = 0; i < 64; ++i) {
    const float hc = hs[i][lane];
    const int base = i * 8;
    float z0 = fmaf(hc, w1p[base + 0], b1p[base + 0]);
    float z1 = fmaf(hc, w1p[base + 1], b1p[base + 1]);
    float z2 = fmaf(hc, w1p[base + 2], b1p[base + 2]);
    float z3 = fmaf(hc, w1p[base + 3], b1p[base + 3]);
    float z4 = fmaf(hc, w1p[base + 4], b1p[base + 4]);
    float z5 = fmaf(hc, w1p[base + 5], b1p[base + 5]);
    float z6 = fmaf(hc, w1p[base + 6], b1p[base + 6]);
    float z7 = fmaf(hc, w1p[base + 7], b1p[base + 7]);
    float s0 = rcp_nr(1.0f + __builtin_amdgcn_exp2f(z0));
    float s1 = rcp_nr(1.0f + __builtin_amdgcn_exp2f(z1));
    float s2 = rcp_nr(1.0f + __builtin_amdgcn_exp2f(z2));
    float s3 = rcp_nr(1.0f + __builtin_amdgcn_exp2f(z3));
    float s4 = rcp_nr(1.0f + __builtin_amdgcn_exp2f(z4));
    float s5 = rcp_nr(1.0f + __builtin_amdgcn_exp2f(z5));
    float s6 = rcp_nr(1.0f + __builtin_amdgcn_exp2f(z6));
    float s7 = rcp_nr(1.0f + __builtin_amdgcn_exp2f(z7));
    a0 = fmaf(w2p[base + 0], s0, a0);
    a1 = fmaf(w2p[base + 1], s1, a1);
    a2 = fmaf(w2p[base + 2], s2, a2);
    a3 = fmaf(w2p[base + 3], s3, a3);
    a4 = fmaf(w2p[base + 4], s4, a4);
    a5 = fmaf(w2p[base + 5], s5, a5);
    a6 = fmaf(w2p[base + 6], s6, a6);
    a7 = fmaf(w2p[base + 7], s7, a7);
  }

  const float acc = ((a0 + a1) + (a2 + a3)) + ((a4 + a5) + (a6 + a7));
  const float y = S - 2.f * acc;
  const float e = __builtin_amdgcn_exp2f(y * C2L);
  const float r = __builtin_amdgcn_rcpf(1.0f + e);
  hout[j * 8192 + n] = fmaf(r, -2.f * C2L, C2L);   // C2L * tanh(y)
}

// ---------------- K2: layer2 + head (r3-replica control, hw rcp) ----------------
__global__ __launch_bounds__(256, 8) void kan_layer2(
    const float* __restrict__ hin,   // [64][8192] = C2L * h1
    const float* __restrict__ W1,    // (64,64,8)
    const float* __restrict__ B1c,   // (64,64,8) = C2L * B1
    const float* __restrict__ W2,    // (64,64,8)
    const float* __restrict__ B2,    // (64,64)
    const float* __restrict__ Wout,  // (1,64)
    float* __restrict__ out)         // (8192,) += partials
{
  __shared__ float hs[64][64];
  __shared__ float red[4][64];
  const int tid  = threadIdx.x;
  const int lane = tid & 63;
  const int wave = __builtin_amdgcn_readfirstlane(tid >> 6);
  const int n    = blockIdx.x * 64 + lane;

#pragma unroll
  for (int r = 0; r < 16; ++r) {
    const int i = r * 4 + wave;
    hs[i][lane] = hin[i * 8192 + n];
  }
  __syncthreads();

  const int j = blockIdx.y * 4 + wave;
  const float* __restrict__ w1p = W1  + j * 512;
  const float* __restrict__ b1p = B1c + j * 512;
  const float* __restrict__ w2p = W2  + j * 512;

  float sp = B2[j * 64 + lane];
  {
    const float4* w2v = (const float4*)w2p;
    float4 va = w2v[lane * 2 + 0];
    float4 vb = w2v[lane * 2 + 1];
    sp += (va.x + va.y) + (va.z + va.w) + (vb.x + vb.y) + (vb.z + vb.w);
  }
#pragma unroll
  for (int off = 32; off; off >>= 1) sp += __shfl_xor(sp, off);
  const float S = sp;

  float acc0 = 0.f, acc1 = 0.f, acc2 = 0.f, acc3 = 0.f;
  for (int i = 0; i < 64; ++i) {
    const float hc = hs[i][lane];
    const int base = i * 8;
#pragma unroll
    for (int k = 0; k < 8; k += 4) {
      float z0 = fmaf(hc, w1p[base + k + 0], b1p[base + k + 0]);
      float z1 = fmaf(hc, w1p[base + k + 1], b1p[base + k + 1]);
      float z2 = fmaf(hc, w1p[base + k + 2], b1p[base + k + 2]);
      float z3 = fmaf(hc, w1p[base + k + 3], b1p[base + k + 3]);
      float s0 = __builtin_amdgcn_rcpf(1.0f + __builtin_amdgcn_exp2f(z0));
      float s1 = __builtin_amdgcn_rcpf(1.0f + __builtin_amdgcn_exp2f(z1));
      float s2 = __builtin_amdgcn_rcpf(1.0f + __builtin_amdgcn_exp2f(z2));
      float s3 = __builtin_amdgcn_rcpf(1.0f + __builtin_amdgcn_exp2f(z3));
      acc0 = fmaf(w2p[base + k + 0], s0, acc0);
      acc1 = fmaf(w2p[base + k + 1], s1, acc1);
      acc2 = fmaf(w2p[base + k + 2], s2, acc2);
      acc3 = fmaf(w2p[base + k + 3], s3, acc3);
    }
  }

  const float y = S - 2.f * ((acc0 + acc1) + (acc2 + acc3));
  const float e = __builtin_amdgcn_exp2f(y * C2L);
  const float r = __builtin_amdgcn_rcpf(1.0f + e);
  const float h2 = fmaf(r, -2.f, 1.f);           // tanh(y)

  red[wave][lane] = h2 * Wout[j];
  __syncthreads();
  if (wave == 0) {
    const float pblk = (red[0][lane] + red[1][lane]) + (red[2][lane] + red[3][lane]);
    atomicAdd(&out[n], pblk);
  }
}

extern "C" void kernel_launch(void* const* d_in, const int* in_sizes, int n_in,
                              void* d_out, int out_size, void* d_ws, size_t ws_size,
                              hipStream_t stream) {
  const float* x    = (const float*)d_in[0];
  const float* t    = (const float*)d_in[1];
  const float* W1_0 = (const float*)d_in[2];
  const float* B1_0 = (const float*)d_in[3];
  const float* W2_0 = (const float*)d_in[4];
  const float* B2_0 = (const float*)d_in[5];
  const float* W1_1 = (const float*)d_in[6];
  const float* B1_1 = (const float*)d_in[7];
  const float* W2_1 = (const float*)d_in[8];
  const float* B2_1 = (const float*)d_in[9];
  const float* W1_2 = (const float*)d_in[10];
  const float* B1_2 = (const float*)d_in[11];
  const float* W2_2 = (const float*)d_in[12];
  const float* B2_2 = (const float*)d_in[13];
  const float* Wout = (const float*)d_in[14];
  const float* bout = (const float*)d_in[15];
  float* out = (float*)d_out;

  float* hA   = (float*)d_ws;          // [64][8192] = 2 MB
  float* hB   = hA + 64 * 8192;        // [64][8192] = 2 MB
  float* B1c1 = hB + 64 * 8192;        // 32768 floats
  float* B1c2 = B1c1 + 32768;          // 32768 floats

  kan_layer0<<<dim3(128, 4), 256, 0, stream>>>(
      x, t, W1_0, B1_0, W2_0, B2_0, B1_1, B1_2, bout, hA, B1c1, B1c2, out);
  kan_layer1<<<dim3(128, 16), 256, 0, stream>>>(hA, W1_1, B1c1, W2_1, B2_1, hB);
  kan_layer2<<<dim3(128, 16), 256, 0, stream>>>(hB, W1_2, B1c2, W2_2, B2_2, Wout, out);
}